// Round 3
// baseline (35297.369 us; speedup 1.0000x reference)
//
#include <hip/hip_runtime.h>
#include <math.h>

// ESN recurrence: x_t = tanh(w_in*u_t + W x_{t-1}); out[t-washout] = c . x_t
// R17 = R16 (8x replicated single-hop tagged-pair exchange, 32.9ms) with the
// detection retry loop upgraded from SERIALIZED sweeps to a 3-DEEP STAGGERED
// rotation on pending elements.
// Calibration from R15/R16: one LLC hop ~0.7us (R15: +2 hops = +1.39us/step);
// contention falsified (R16: 8x fewer pollers/line = neutral). R14 chain
// model: commit 0.7 + detect + compute 0.5-0.8 = 2.1-2.5us, measured 4.05us.
// Residual ~1.6us attributed to sweep QUANTIZATION: a pending element is only
// reloaded after the previous load returned stale -> detection advances in
// 0.7us quanta; publish spread ~1 sweep sustains 2-3 sweeps/step.
// Fix: per pending element keep 3 staggered loads in flight (check oldest,
// promote, reissue) -> sampling cadence ~RT/3. Pollers/line already cut 8x
// by replication; s_sleep(1) paces the rotation so hot-line request rate
// stays under LLC bank service (why naive 2-deep lost in R14).
// Also: publish spread across lanes 0..15 (1 xchg each) for faster issue.
// Prediction: quantization-dominated -> 3.0-3.4us/step (25-28ms), FETCH up
// 10-30%; neutral -> detection already single-sweep, residual is elsewhere
// (clock/compute) -> next round overlaps compute under detection or floors.

#define H_   2048
#define RPB  8          // rows per block
#define NBLK 256
#define NREP 8          // value-buffer replicas
typedef unsigned long long ull;
// ws layout (float idx):
//   [0, 65536)      ull xval[NREP][2][2048]: per-replica, per-parity
//                   (epoch<<32 | value) for each x element. 256 KB.
//   [65536, 67584)  float c (scatter of w_out by mask)
//   [67584, 67584+T*256)  part (per-step per-block partials, plain store)

__global__ void esn_zero(float* __restrict__ p, int n)
{
    int i = blockIdx.x * blockDim.x + threadIdx.x;
    int stride = gridDim.x * blockDim.x;
    for (; i < n; i += stride) p[i] = 0.0f;
}

__global__ __launch_bounds__(1024) void esn_scatter_c(const int* __restrict__ mask,
                                                      const float* __restrict__ w_out,
                                                      float* __restrict__ ws_f, int H)
{
    float* c = ws_f + 65536;
    for (int i = threadIdx.x; i < H; i += blockDim.x)
        atomicAdd(&c[mask[i]], w_out[i]);
}

__global__ __launch_bounds__(256) void esn_run(const float* __restrict__ u,
                                               const float* __restrict__ w_res,
                                               const float* __restrict__ w_in,
                                               float* __restrict__ out,
                                               float* __restrict__ ws_f,
                                               int T, int washout, int use_part)
{
    __shared__ float Wlds[RPB * H_];   // 64 KB
    __shared__ float xs[H_];
    __shared__ float psum[4];

    const int tid  = threadIdx.x;
    const int wave = tid >> 6;
    const int lane = tid & 63;
    const int bid  = blockIdx.x;
    const int r0 = 2 * wave;
    const int grow0 = bid * RPB + r0, grow1 = grow0 + 1;

    {
        const float4* src = (const float4*)(w_res + (size_t)bid * RPB * H_);
        float4* dst = (float4*)Wlds;
        for (int i = tid; i < RPB * H_ / 4; i += 256) dst[i] = src[i];
    }
    float win0 = 0.f, win1 = 0.f, c0 = 0.f, c1 = 0.f;
    if (lane == 0) {
        win0 = w_in[grow0]; win1 = w_in[grow1];
        c0 = ws_f[65536 + grow0]; c1 = ws_f[65536 + grow1];
    }

    ull* xv = (ull*)ws_f;              // [NREP][2][2048]
    float* part = ws_f + 67584;

    const float4* w0p = (const float4*)(Wlds + r0 * H_);
    const float4* w1p = (const float4*)(Wlds + (r0 + 1) * H_);
    const float4* xs4 = (const float4*)xs;

    // this block reads replica (bid & 7) only
    const ull* rbase = xv + (size_t)(bid & (NREP - 1)) * 4096;

    float u_next = u[0];
    __syncthreads();   // Wlds ready

    for (int k = 0; k < T; ++k) {
        const ull* sp = rbase + (k & 1) * 2048;
        float uk = u_next;
        if (k + 1 < T) u_next = u[k + 1];

        // ---- stage x_k: batch load, then 3-deep staggered retry on pending ----
        ull pa[8];
#pragma unroll
        for (int i = 0; i < 8; ++i)
            pa[i] = __hip_atomic_load(sp + (i << 8) + tid, __ATOMIC_RELAXED,
                                      __HIP_MEMORY_SCOPE_AGENT);
        unsigned pend = 0;
#pragma unroll
        for (int i = 0; i < 8; ++i)
            if ((unsigned)(pa[i] >> 32) != (unsigned)k) pend |= (1u << i);
        if (pend) {
            ull pb[8], pc[8];
#pragma unroll
            for (int i = 0; i < 8; ++i)
                if (pend & (1u << i))
                    pb[i] = __hip_atomic_load(sp + (i << 8) + tid, __ATOMIC_RELAXED,
                                              __HIP_MEMORY_SCOPE_AGENT);
#pragma unroll
            for (int i = 0; i < 8; ++i)
                if (pend & (1u << i))
                    pc[i] = __hip_atomic_load(sp + (i << 8) + tid, __ATOMIC_RELAXED,
                                              __HIP_MEMORY_SCOPE_AGENT);
            int spins = 0;
            for (;;) {
                unsigned np = 0;
#pragma unroll
                for (int i = 0; i < 8; ++i)
                    if (pend & (1u << i)) {
                        if ((unsigned)(pa[i] >> 32) != (unsigned)k) {
                            pa[i] = pb[i];
                            pb[i] = pc[i];
                            pc[i] = __hip_atomic_load(sp + (i << 8) + tid,
                                                      __ATOMIC_RELAXED,
                                                      __HIP_MEMORY_SCOPE_AGENT);
                            np |= (1u << i);
                        }
                    }
                pend = np;
                if (!pend) break;
                __builtin_amdgcn_s_sleep(1);   // pace hot-line request rate
                if (++spins > 500000) break;   // failsafe
            }
        }
#pragma unroll
        for (int i = 0; i < 8; ++i)
            xs[(i << 8) + tid] = __uint_as_float((unsigned)pa[i]);
        __syncthreads();

        // ---- dot: wave owns rows r0, r0+1 ----
        float4 a0 = {0.f,0.f,0.f,0.f}, a1 = {0.f,0.f,0.f,0.f};
#pragma unroll
        for (int c = 0; c < 8; ++c) {
            float4 xvv = xs4[c * 64 + lane];
            float4 wv0 = w0p[c * 64 + lane];
            float4 wv1 = w1p[c * 64 + lane];
            a0.x = fmaf(wv0.x, xvv.x, a0.x); a0.y = fmaf(wv0.y, xvv.y, a0.y);
            a0.z = fmaf(wv0.z, xvv.z, a0.z); a0.w = fmaf(wv0.w, xvv.w, a0.w);
            a1.x = fmaf(wv1.x, xvv.x, a1.x); a1.y = fmaf(wv1.y, xvv.y, a1.y);
            a1.z = fmaf(wv1.z, xvv.z, a1.z); a1.w = fmaf(wv1.w, xvv.w, a1.w);
        }
        float s0 = (a0.x + a0.y) + (a0.z + a0.w);
        float s1 = (a1.x + a1.y) + (a1.z + a1.w);
#pragma unroll
        for (int d = 1; d < 64; d <<= 1) {
            s0 += __shfl_xor(s0, d);
            s1 += __shfl_xor(s1, d);
        }

        ull p0 = 0, p1 = 0;
        if (lane == 0) {
            float z0 = fmaf(win0, uk, s0);
            float z1 = fmaf(win1, uk, s1);
            z0 = fminf(fmaxf(z0, -15.f), 15.f);
            z1 = fminf(fmaxf(z1, -15.f), 15.f);
            float e0 = __expf(2.f * z0), e1 = __expf(2.f * z1);
            float t0 = (e0 - 1.f) / (e0 + 1.f), t1 = (e1 - 1.f) / (e1 + 1.f);
            p0 = ((ull)(unsigned)(k + 1) << 32) | (ull)__float_as_uint(t0);
            p1 = ((ull)(unsigned)(k + 1) << 32) | (ull)__float_as_uint(t1);
            psum[wave] = c0 * t0 + c1 * t1;
        }
        // broadcast tagged pairs; lanes 0..15 publish one xchg each:
        // lane<8 -> row grow0 to replica lane; lane>=8 -> row grow1 to replica lane-8
        p0 = __shfl(p0, 0, 64);
        p1 = __shfl(p1, 0, 64);
        if (lane < 2 * NREP) {
            int rep = lane & (NREP - 1);
            ull* dpr = xv + (size_t)rep * 4096 + ((k + 1) & 1) * 2048;
            int   row = (lane < NREP) ? grow0 : grow1;
            ull   val = (lane < NREP) ? p0 : p1;
            // exchange: commits at the far unit (no writeback lag)
            (void)__hip_atomic_exchange(dpr + row, val, __ATOMIC_RELAXED,
                                        __HIP_MEMORY_SCOPE_AGENT);
        }
        __syncthreads();   // psum ready; xs reads done (safe to restage)

        if (tid == 0) {
            float pw = (psum[0] + psum[1]) + (psum[2] + psum[3]);
            if (use_part) part[(size_t)k * NBLK + bid] = pw;
            else if (k >= washout) atomicAdd(&out[k - washout], pw);
        }
    }
}

__global__ __launch_bounds__(256) void esn_reduce(const float* __restrict__ part,
                                                  float* __restrict__ out,
                                                  int out_size, int washout)
{
    int wv = threadIdx.x >> 6, lane = threadIdx.x & 63;
    int t = blockIdx.x * 4 + wv;
    if (t >= out_size) return;
    const float4* p = (const float4*)(part + (size_t)(t + washout) * NBLK);
    float4 v = p[lane];
    float s = (v.x + v.y) + (v.z + v.w);
#pragma unroll
    for (int d = 1; d < 64; d <<= 1) s += __shfl_xor(s, d);
    if (lane == 0) out[t] = s;
}

extern "C" void kernel_launch(void* const* d_in, const int* in_sizes, int n_in,
                              void* d_out, int out_size, void* d_ws, size_t ws_size,
                              hipStream_t stream)
{
    const float* u     = (const float*)d_in[0];
    const float* w_res = (const float*)d_in[1];
    const float* w_in  = (const float*)d_in[2];
    const float* w_out = (const float*)d_in[3];
    const int*   mask  = (const int*)d_in[4];
    int T = in_sizes[0];
    int H = in_sizes[2];
    int washout = T - out_size;
    float* out  = (float*)d_out;
    float* ws_f = (float*)d_ws;

    size_t need = (size_t)(67584 + (size_t)T * NBLK) * 4;
    int use_part = (ws_size >= need) ? 1 : 0;

    hipLaunchKernelGGL(esn_zero, dim3(128), dim3(256), 0, stream, ws_f, 67584);
    if (!use_part)   // direct-atomic fallback needs out pre-zeroed
        hipLaunchKernelGGL(esn_zero, dim3(32), dim3(256), 0, stream, out, out_size);
    hipLaunchKernelGGL(esn_scatter_c, dim3(1), dim3(1024), 0, stream, mask, w_out, ws_f, H);

    void* args[] = { (void*)&u, (void*)&w_res, (void*)&w_in, (void*)&out,
                     (void*)&ws_f, (void*)&T, (void*)&washout, (void*)&use_part };
    hipError_t e = hipLaunchCooperativeKernel((const void*)esn_run,
                                              dim3(NBLK), dim3(256),
                                              args, 0, stream);
    if (e != hipSuccess) {
        hipLaunchKernelGGL(esn_run, dim3(NBLK), dim3(256), 0, stream,
                           u, w_res, w_in, out, ws_f, T, washout, use_part);
    }
    if (use_part)
        hipLaunchKernelGGL(esn_reduce, dim3((out_size + 3) / 4), dim3(256), 0, stream,
                           ws_f + 67584, out, out_size, washout);
}